// Round 1
// baseline (386.793 us; speedup 1.0000x reference)
//
#include <hip/hip_runtime.h>

// GaussianConditionalStanh: symbols = searchsorted(mid, x - mean) (nearest
// codebook level, side='left'); dequant = codebook[symbols] + mean.
// Memory-bound: ~453 MB HBM traffic -> ~72 us floor at 6.3 TB/s.

namespace {

constexpr int kL = 60;        // codebook size (reference L)
constexpr int kMid = kL - 1;  // decision boundaries

__global__ __launch_bounds__(256) void stanh_quant_kernel(
    const float* __restrict__ x,
    const float* __restrict__ mean,
    const float* __restrict__ cb,
    float* __restrict__ sym_out,
    float* __restrict__ deq_out,
    int n4)
{
    // Codebook in LDS for the divergent gather in the epilogue.
    __shared__ float cb_lds[kL];
    if (threadIdx.x < kL) cb_lds[threadIdx.x] = cb[threadIdx.x];
    __syncthreads();

    // Midpoints hoisted into registers once per thread; EXACT same f32
    // arithmetic as reference: 0.5f * (cb[i] + cb[i+1]).
    float mid[kMid];
#pragma unroll
    for (int i = 0; i < kMid; ++i) mid[i] = 0.5f * (cb[i] + cb[i + 1]);

    const float4* __restrict__ x4 = (const float4*)x;
    const float4* __restrict__ m4 = (const float4*)mean;
    float4* __restrict__ s4 = (float4*)sym_out;
    float4* __restrict__ d4 = (float4*)deq_out;

    const int stride = gridDim.x * blockDim.x;
    for (int g = blockIdx.x * blockDim.x + threadIdx.x; g < n4; g += stride) {
        const float4 xv = x4[g];
        const float4 mv = m4[g];
        const float y0 = xv.x - mv.x;
        const float y1 = xv.y - mv.y;
        const float y2 = xv.z - mv.z;
        const float y3 = xv.w - mv.w;

        // searchsorted(mid, y, side='left') == count(mid[i] < y)
        int i0 = 0, i1 = 0, i2 = 0, i3 = 0;
#pragma unroll
        for (int i = 0; i < kMid; ++i) {
            i0 += (y0 > mid[i]);
            i1 += (y1 > mid[i]);
            i2 += (y2 > mid[i]);
            i3 += (y3 > mid[i]);
        }

        float4 sv;
        sv.x = (float)i0; sv.y = (float)i1; sv.z = (float)i2; sv.w = (float)i3;
        float4 dv;
        dv.x = cb_lds[i0] + mv.x;
        dv.y = cb_lds[i1] + mv.y;
        dv.z = cb_lds[i2] + mv.z;
        dv.w = cb_lds[i3] + mv.w;

        s4[g] = sv;
        d4[g] = dv;
    }
}

}  // namespace

extern "C" void kernel_launch(void* const* d_in, const int* in_sizes, int n_in,
                              void* d_out, int out_size, void* d_ws, size_t ws_size,
                              hipStream_t stream) {
    const float* x    = (const float*)d_in[0];
    const float* mean = (const float*)d_in[1];
    const float* cb   = (const float*)d_in[2];

    const int n = in_sizes[0];          // 28,311,552 (divisible by 4)
    float* sym_out = (float*)d_out;     // outputs concatenated: [symbols | dequant]
    float* deq_out = sym_out + n;

    const int n4 = n / 4;
    const int block = 256;
    int grid = 8192;                    // grid-stride: amortize 59-mid setup
    const int max_grid = (n4 + block - 1) / block;
    if (grid > max_grid) grid = max_grid;

    hipLaunchKernelGGL(stanh_quant_kernel, dim3(grid), dim3(block), 0, stream,
                       x, mean, cb, sym_out, deq_out, n4);
}

// Round 2
// 372.369 us; speedup vs baseline: 1.0387x; 1.0387x over previous
//
#include <hip/hip_runtime.h>
#include <math.h>

// GaussianConditionalStanh: symbols = searchsorted(mid, x - mean, side='left')
// (nearest codebook level), dequant = codebook[symbols] + mean.
//
// R1 post-mortem: linear 59-compare scan cost ~500-700 VALU inst per float4
// -> compute serialized with memory, 137 us vs ~78 us memory floor.
// R2: uniform-grid guess + exact fixup walk over sentinel-padded midpoints in
// LDS. Guess is almost always within +-1 (jitter 0.05 << spacing 0.51); the
// fixup loops enforce the exact searchsorted invariant ms[g] < y <= ms[g+1],
// so the result is bit-exact independent of the guess quality.

namespace {

constexpr int kL = 60;  // codebook size

__device__ __forceinline__ int find_idx(float y, const float* __restrict__ ms,
                                        float c0, float invd) {
    // initial guess in level space (any value works; fixup makes it exact)
    float t = (y - c0) * invd + 0.5f;
    int g = (int)t;                       // trunc; clamp below
    g = max(0, min(g, kL - 1));
    // ms[0] = -inf, ms[1..59] = mid[0..58], ms[60..63] = +inf
    while (y > ms[g + 1]) ++g;            // ascend; inf sentinel stops at 59
    while (y <= ms[g]) --g;               // descend; -inf sentinel stops at 0
    return g;                             // == count(mid < y)
}

__global__ __launch_bounds__(256) void stanh_quant_kernel(
    const float* __restrict__ x,
    const float* __restrict__ mean,
    const float* __restrict__ cb,
    float* __restrict__ sym_out,
    float* __restrict__ deq_out,
    int n4)
{
    __shared__ float cb_s[kL];
    __shared__ float ms[kL + 4];   // sentinel-padded midpoints

    const int tid = threadIdx.x;
    if (tid < kL) cb_s[tid] = cb[tid];
    if (tid == 0) ms[0] = -INFINITY;
    if (tid < kL - 1) ms[tid + 1] = 0.5f * (cb[tid] + cb[tid + 1]);  // exact ref arith
    if (tid >= kL - 1 && tid < kL + 3) ms[tid + 1] = INFINITY;       // ms[60..63]
    __syncthreads();

    // uniform-grid model (wave-uniform scalar math, s_load'ed)
    const float c0 = cb[0];
    const float invd = 59.0f / (cb[kL - 1] - c0);

    const float4* __restrict__ x4 = (const float4*)x;
    const float4* __restrict__ m4 = (const float4*)mean;
    float4* __restrict__ s4 = (float4*)sym_out;
    float4* __restrict__ d4 = (float4*)deq_out;

    const int stride = gridDim.x * blockDim.x;
    for (int g = blockIdx.x * blockDim.x + tid; g < n4; g += stride) {
        const float4 xv = x4[g];
        const float4 mv = m4[g];
        const float y0 = xv.x - mv.x;
        const float y1 = xv.y - mv.y;
        const float y2 = xv.z - mv.z;
        const float y3 = xv.w - mv.w;

        const int i0 = find_idx(y0, ms, c0, invd);
        const int i1 = find_idx(y1, ms, c0, invd);
        const int i2 = find_idx(y2, ms, c0, invd);
        const int i3 = find_idx(y3, ms, c0, invd);

        float4 sv;
        sv.x = (float)i0; sv.y = (float)i1; sv.z = (float)i2; sv.w = (float)i3;
        float4 dv;
        dv.x = cb_s[i0] + mv.x;
        dv.y = cb_s[i1] + mv.y;
        dv.z = cb_s[i2] + mv.z;
        dv.w = cb_s[i3] + mv.w;

        s4[g] = sv;
        d4[g] = dv;
    }
}

}  // namespace

extern "C" void kernel_launch(void* const* d_in, const int* in_sizes, int n_in,
                              void* d_out, int out_size, void* d_ws, size_t ws_size,
                              hipStream_t stream) {
    const float* x    = (const float*)d_in[0];
    const float* mean = (const float*)d_in[1];
    const float* cb   = (const float*)d_in[2];

    const int n = in_sizes[0];          // 28,311,552 (divisible by 4)
    float* sym_out = (float*)d_out;     // outputs concatenated: [symbols | dequant]
    float* deq_out = sym_out + n;

    const int n4 = n / 4;
    const int block = 256;
    int grid = 8192;                    // grid-stride, ~3.4 float4/thread
    const int max_grid = (n4 + block - 1) / block;
    if (grid > max_grid) grid = max_grid;

    hipLaunchKernelGGL(stanh_quant_kernel, dim3(grid), dim3(block), 0, stream,
                       x, mean, cb, sym_out, deq_out, n4);
}